// Round 7
// baseline (96.010 us; speedup 1.0000x reference)
//
#include <hip/hip_runtime.h>
#include <stdint.h>

// NormalizedCutLoss via MFMA, round 6: tj-outer loop, log2-domain exponent,
// and a wave-uniform underflow guard: per tj-group (4 tiles), if every
// E2 < -126 then exp2 == 0.0f exactly -> skip the 16 exp+fma. Exact for any
// data; fast because off-diagonal exponents here are ~ -6600.

#define P2 256
#define CF 32
#define ROWP 40   // bf16 row pitch: 80B, keeps 16B alignment for b128 reads

using bf16x8 = __attribute__((ext_vector_type(8))) short;
using f32x4  = __attribute__((ext_vector_type(4))) float;

__device__ __forceinline__ short f2bf(float x) {
    union { float f; uint32_t u; } v; v.f = x;
    uint32_t r = (v.u + 0x7FFFu + ((v.u >> 16) & 1u)) >> 16;   // RNE
    return (short)r;
}

__global__ __launch_bounds__(256, 4)
void ncut_mfma_kernel(const float* __restrict__ pred,
                      const float* __restrict__ feat,
                      float* __restrict__ out)
{
    __shared__ short  fb[P2][ROWP];   // bf16 features [pixel][channel]
    __shared__ float2 sp[P2];         // {sq(f32), p}
    __shared__ float  red[8];

    const int t  = threadIdx.x;
    const int l  = t & 63;
    const int w  = t >> 6;
    const int b  = blockIdx.x;
    const int n  = b >> 8, pl = b & 255;
    const int hp = pl >> 4, wp = pl & 15;
    const int py = t >> 4,  px = t & 15;
    const int row = hp * 16 + py, col = wp * 16 + px;

    // ---- stage: 32 channels of own pixel -> bf16 LDS; sq in f32 ----
    const float* fbase = feat + (((size_t)n * CF) * 256 + row) * 256 + col;
    float sq = 0.f;
    short mybf[CF];
#pragma unroll
    for (int c = 0; c < CF; ++c) {
        float v = fbase[(size_t)c * 65536];
        sq = fmaf(v, v, sq);
        mybf[c] = f2bf(v);
    }
#pragma unroll
    for (int q = 0; q < 4; ++q)
        *(bf16x8*)&fb[t][q * 8] = *(const bf16x8*)&mybf[q * 8];
    const float p_i = pred[((size_t)n * 256 + row) * 256 + col];
    sp[t] = make_float2(sq, p_i);
    __syncthreads();

    const int lr = l & 15;   // col-in-tile (pixel j = tj*16+lr)
    const int lk = l >> 4;   // k-group; acc rows qi = lk*4+r

    // A-fragments for this wave's 4 row-tiles (ti = w*4+tii)
    bf16x8 af[4];
#pragma unroll
    for (int r = 0; r < 4; ++r)
        af[r] = *(const bf16x8*)&fb[(w * 4 + r) * 16 + lr][lk * 8];

    // log2-domain: E2 = L100*dot - L50*(sq_i+sq_j) + CSPL*dsp_px2
    const float L50  = 72.134752f;      // 50*log2(e)
    const float L100 = 144.269504f;     // 100*log2(e)
    const float CSPL = -4.3333804e-8f;  // -log2(e)/(2*256*65025)

    // a[tii][r] = CSPL*(qi-lr)^2 - L50*sq_i
    float a[4][4];
    float api[4][4];
#pragma unroll
    for (int tii = 0; tii < 4; ++tii)
#pragma unroll
        for (int r = 0; r < 4; ++r) {
            const int qi = lk * 4 + r;
            const float dq = (float)(qi - lr);
            a[tii][r] = fmaf(dq * dq, CSPL, -L50 * sp[(w * 4 + tii) * 16 + qi].x);
            api[tii][r] = 0.f;
        }

    const f32x4 zero = {0.f, 0.f, 0.f, 0.f};
    const float tif = (float)(w * 4);

#pragma unroll 2
    for (int tj = 0; tj < 16; ++tj) {
        const bf16x8 bfj = *(const bf16x8*)&fb[tj * 16 + lr][lk * 8];
        const float2 spc = sp[tj * 16 + lr];          // {sq_j, p_j}
        const float bbase = -L50 * spc.x;
        const float tjf = (float)tj;

        // 4 independent MFMAs for this tj-group, then 16 E2 values
        f32x4 acc[4];
#pragma unroll
        for (int tii = 0; tii < 4; ++tii)
            acc[tii] = __builtin_amdgcn_mfma_f32_16x16x32_bf16(af[tii], bfj, zero, 0, 0, 0);

        float E[4][4];
        float mx = -1e30f;
#pragma unroll
        for (int tii = 0; tii < 4; ++tii) {
            const float dyf = tif + (float)tii - tjf;
            const float bj = fmaf(dyf * dyf, CSPL, bbase);
#pragma unroll
            for (int r = 0; r < 4; ++r) {
                E[tii][r] = fmaf(L100, acc[tii][r], a[tii][r] + bj);
                mx = fmaxf(mx, E[tii][r]);
            }
        }

        // exp2(x) == 0.0f exactly for x < -149; guard at -126 (normal floor)
        if (__any(mx > -126.f)) {
#pragma unroll
            for (int tii = 0; tii < 4; ++tii) {
                const bool tdiag = (w * 4 + tii) == tj;
#pragma unroll
                for (int r = 0; r < 4; ++r) {
                    float e2 = E[tii][r];
                    if (tdiag && (lk * 4 + r) == lr) e2 = 0.f;  // exact diagonal
                    api[tii][r] = fmaf(__builtin_amdgcn_exp2f(e2), spc.y, api[tii][r]);
                }
            }
        }
    }

    // ---- reduce Ap over the 16 lanes sharing lk; then patch loss ----
    float assoc = 0.f, cut = 0.f;
#pragma unroll
    for (int tii = 0; tii < 4; ++tii)
#pragma unroll
        for (int r = 0; r < 4; ++r) {
            float v = api[tii][r];
            v += __shfl_xor(v, 1);
            v += __shfl_xor(v, 2);
            v += __shfl_xor(v, 4);
            v += __shfl_xor(v, 8);
            if (lr == 0) {
                const float pi = sp[(w * 4 + tii) * 16 + lk * 4 + r].y;
                assoc += v;
                cut   += (1.f - pi) * v;
            }
        }

#pragma unroll
    for (int off = 32; off; off >>= 1) {
        assoc += __shfl_down(assoc, off);
        cut   += __shfl_down(cut,  off);
    }
    if (l == 0) { red[2 * w] = assoc; red[2 * w + 1] = cut; }
    __syncthreads();
    if (t == 0) {
        float aa = red[0] + red[2] + red[4] + red[6];
        float cc = red[1] + red[3] + red[5] + red[7];
        atomicAdd(out, (cc / (aa + 1e-5f)) * (1.0f / 1024.0f));
    }
}

extern "C" void kernel_launch(void* const* d_in, const int* in_sizes, int n_in,
                              void* d_out, int out_size, void* d_ws, size_t ws_size,
                              hipStream_t stream)
{
    const float* pred = (const float*)d_in[0];   // (4,1,256,256) f32
    const float* feat = (const float*)d_in[1];   // (4,32,256,256) f32
    float* out = (float*)d_out;                  // scalar f32

    hipMemsetAsync(out, 0, sizeof(float) * out_size, stream);
    ncut_mfma_kernel<<<1024, 256, 0, stream>>>(pred, feat, out);
}

// Round 8
// 91.027 us; speedup vs baseline: 1.0547x; 1.0547x over previous
//
#include <hip/hip_runtime.h>
#include <stdint.h>

// Round 8: identical compute to round 6 (MFMA + log2-domain + underflow guard),
// but the single-address atomicAdd tail (1024 same-line device-scope RMWs in a
// lockstep burst) is replaced by per-patch stores to d_ws + a tiny reduce kernel.

#define P2 256
#define CF 32
#define ROWP 40   // bf16 row pitch: 80B, keeps 16B alignment for b128 reads

using bf16x8 = __attribute__((ext_vector_type(8))) short;
using f32x4  = __attribute__((ext_vector_type(4))) float;

__device__ __forceinline__ short f2bf(float x) {
    union { float f; uint32_t u; } v; v.f = x;
    uint32_t r = (v.u + 0x7FFFu + ((v.u >> 16) & 1u)) >> 16;   // RNE
    return (short)r;
}

__global__ __launch_bounds__(256, 4)
void ncut_mfma_kernel(const float* __restrict__ pred,
                      const float* __restrict__ feat,
                      float* __restrict__ ws)
{
    __shared__ short  fb[P2][ROWP];   // bf16 features [pixel][channel]
    __shared__ float2 sp[P2];         // {sq(f32), p}
    __shared__ float  red[8];

    const int t  = threadIdx.x;
    const int l  = t & 63;
    const int w  = t >> 6;
    const int b  = blockIdx.x;
    const int n  = b >> 8, pl = b & 255;
    const int hp = pl >> 4, wp = pl & 15;
    const int py = t >> 4,  px = t & 15;
    const int row = hp * 16 + py, col = wp * 16 + px;

    // ---- stage: 32 channels of own pixel -> bf16 LDS; sq in f32 ----
    const float* fbase = feat + (((size_t)n * CF) * 256 + row) * 256 + col;
    float sq = 0.f;
    short mybf[CF];
#pragma unroll
    for (int c = 0; c < CF; ++c) {
        float v = fbase[(size_t)c * 65536];
        sq = fmaf(v, v, sq);
        mybf[c] = f2bf(v);
    }
#pragma unroll
    for (int q = 0; q < 4; ++q)
        *(bf16x8*)&fb[t][q * 8] = *(const bf16x8*)&mybf[q * 8];
    const float p_i = pred[((size_t)n * 256 + row) * 256 + col];
    sp[t] = make_float2(sq, p_i);
    __syncthreads();

    const int lr = l & 15;   // col-in-tile (pixel j = tj*16+lr)
    const int lk = l >> 4;   // k-group; acc rows qi = lk*4+r

    bf16x8 af[4];
#pragma unroll
    for (int r = 0; r < 4; ++r)
        af[r] = *(const bf16x8*)&fb[(w * 4 + r) * 16 + lr][lk * 8];

    // log2-domain: E2 = L100*dot - L50*(sq_i+sq_j) + CSPL*dsp_px2
    const float L50  = 72.134752f;      // 50*log2(e)
    const float L100 = 144.269504f;     // 100*log2(e)
    const float CSPL = -4.3333804e-8f;  // -log2(e)/(2*256*65025)

    float a[4][4];
    float api[4][4];
#pragma unroll
    for (int tii = 0; tii < 4; ++tii)
#pragma unroll
        for (int r = 0; r < 4; ++r) {
            const int qi = lk * 4 + r;
            const float dq = (float)(qi - lr);
            a[tii][r] = fmaf(dq * dq, CSPL, -L50 * sp[(w * 4 + tii) * 16 + qi].x);
            api[tii][r] = 0.f;
        }

    const f32x4 zero = {0.f, 0.f, 0.f, 0.f};
    const float tif = (float)(w * 4);

#pragma unroll 2
    for (int tj = 0; tj < 16; ++tj) {
        const bf16x8 bfj = *(const bf16x8*)&fb[tj * 16 + lr][lk * 8];
        const float2 spc = sp[tj * 16 + lr];          // {sq_j, p_j}
        const float bbase = -L50 * spc.x;
        const float tjf = (float)tj;

        f32x4 acc[4];
#pragma unroll
        for (int tii = 0; tii < 4; ++tii)
            acc[tii] = __builtin_amdgcn_mfma_f32_16x16x32_bf16(af[tii], bfj, zero, 0, 0, 0);

        float E[4][4];
        float mx = -1e30f;
#pragma unroll
        for (int tii = 0; tii < 4; ++tii) {
            const float dyf = tif + (float)tii - tjf;
            const float bj = fmaf(dyf * dyf, CSPL, bbase);
#pragma unroll
            for (int r = 0; r < 4; ++r) {
                E[tii][r] = fmaf(L100, acc[tii][r], a[tii][r] + bj);
                mx = fmaxf(mx, E[tii][r]);
            }
        }

        // exp2(x) < -126 underflows to exactly 0.0f -> skip
        if (__any(mx > -126.f)) {
#pragma unroll
            for (int tii = 0; tii < 4; ++tii) {
                const bool tdiag = (w * 4 + tii) == tj;
#pragma unroll
                for (int r = 0; r < 4; ++r) {
                    float e2 = E[tii][r];
                    if (tdiag && (lk * 4 + r) == lr) e2 = 0.f;  // exact diagonal
                    api[tii][r] = fmaf(__builtin_amdgcn_exp2f(e2), spc.y, api[tii][r]);
                }
            }
        }
    }

    // ---- reduce Ap over the 16 lanes sharing lk; then patch loss ----
    float assoc = 0.f, cut = 0.f;
#pragma unroll
    for (int tii = 0; tii < 4; ++tii)
#pragma unroll
        for (int r = 0; r < 4; ++r) {
            float v = api[tii][r];
            v += __shfl_xor(v, 1);
            v += __shfl_xor(v, 2);
            v += __shfl_xor(v, 4);
            v += __shfl_xor(v, 8);
            if (lr == 0) {
                const float pi = sp[(w * 4 + tii) * 16 + lk * 4 + r].y;
                assoc += v;
                cut   += (1.f - pi) * v;
            }
        }

#pragma unroll
    for (int off = 32; off; off >>= 1) {
        assoc += __shfl_down(assoc, off);
        cut   += __shfl_down(cut,  off);
    }
    if (l == 0) { red[2 * w] = assoc; red[2 * w + 1] = cut; }
    __syncthreads();
    if (t == 0) {
        float aa = red[0] + red[2] + red[4] + red[6];
        float cc = red[1] + red[3] + red[5] + red[7];
        ws[b] = cc / (aa + 1e-5f);     // plain store, no atomic
    }
}

__global__ __launch_bounds__(256)
void ncut_reduce_kernel(const float* __restrict__ ws, float* __restrict__ out)
{
    __shared__ float red[4];
    const int t = threadIdx.x;
    float s = ws[t] + ws[t + 256] + ws[t + 512] + ws[t + 768];
#pragma unroll
    for (int off = 32; off; off >>= 1)
        s += __shfl_down(s, off);
    if ((t & 63) == 0) red[t >> 6] = s;
    __syncthreads();
    if (t == 0)
        out[0] = (red[0] + red[1] + red[2] + red[3]) * (1.0f / 1024.0f);
}

extern "C" void kernel_launch(void* const* d_in, const int* in_sizes, int n_in,
                              void* d_out, int out_size, void* d_ws, size_t ws_size,
                              hipStream_t stream)
{
    const float* pred = (const float*)d_in[0];   // (4,1,256,256) f32
    const float* feat = (const float*)d_in[1];   // (4,32,256,256) f32
    float* out = (float*)d_out;                  // scalar f32
    float* ws  = (float*)d_ws;                   // per-patch losses (1024 f32)

    ncut_mfma_kernel<<<1024, 256, 0, stream>>>(pred, feat, ws);
    ncut_reduce_kernel<<<1, 256, 0, stream>>>(ws, out);
}

// Round 10
// 90.402 us; speedup vs baseline: 1.0620x; 1.0069x over previous
//
#include <hip/hip_runtime.h>
#include <hip/hip_bf16.h>
#include <stdint.h>

// Round 9: vectorized float4 staging (8 loads/thread, quad-transpose in reg,
// sq from f32 during staging), lean weighted epilogue reduce (12 shfl).
// Compute core unchanged: bf16 MFMA Gram + log2-domain exponent + underflow
// guard + exact forced diagonal. No atomics; tiny second reduce kernel.

#define P2 256
#define CF 32
#define ROWP 40   // bf16 row pitch: 80 B (multiple of 16 -> b128-aligned rows)

using bf16x8 = __attribute__((ext_vector_type(8))) short;
using f32x4  = __attribute__((ext_vector_type(4))) float;

__device__ __forceinline__ short bfs(float x) {
    __hip_bfloat16 h = __float2bfloat16(x);   // native RNE convert
    union { __hip_bfloat16 h; short s; } u; u.h = h; return u.s;
}

__global__ __launch_bounds__(256, 4)
void ncut_mfma_kernel(const float* __restrict__ pred,
                      const float* __restrict__ feat,
                      float* __restrict__ ws)
{
    __shared__ short  fb[P2][ROWP];   // bf16 features [pixel][channel]
    __shared__ float2 sp[P2];         // {sq(f32), p}
    __shared__ float  red[8];

    const int t  = threadIdx.x;
    const int l  = t & 63;
    const int w  = t >> 6;
    const int b  = blockIdx.x;
    const int n  = b >> 8, pl = b & 255;
    const int hp = pl >> 4, wp = pl & 15;

    // ---- staging: thread t handles pixel-quad pq = t>>2 (4 px in one row)
    //      and channel-groups cg0 = t&3 and cg0+4 (4 channels each) ----
    const int pq  = t >> 2;        // 0..63
    const int y   = pq >> 2;       // patch row 0..15
    const int k   = pq & 3;        // quad within row (cols k*4..k*4+3)
    const int cg0 = t & 3;

    const float* qbase = feat + (((size_t)n * CF) * 256 + hp * 16 + y) * 256
                              + wp * 16 + k * 4;

    float4 v[8];
#pragma unroll
    for (int it = 0; it < 2; ++it) {
        const int cg = cg0 + it * 4;
#pragma unroll
        for (int cc = 0; cc < 4; ++cc)
            v[it * 4 + cc] = *(const float4*)(qbase + (size_t)(cg * 4 + cc) * 65536);
    }
    const float p_mine = pred[(((size_t)n * 256) + hp * 16 + y) * 256
                              + wp * 16 + k * 4 + cg0];

    // partial sum-of-squares (f32-exact) for the quad's 4 pixels over my 8 ch
    float psq0 = 0.f, psq1 = 0.f, psq2 = 0.f, psq3 = 0.f;
#pragma unroll
    for (int q8 = 0; q8 < 8; ++q8) {
        psq0 = fmaf(v[q8].x, v[q8].x, psq0);
        psq1 = fmaf(v[q8].y, v[q8].y, psq1);
        psq2 = fmaf(v[q8].z, v[q8].z, psq2);
        psq3 = fmaf(v[q8].w, v[q8].w, psq3);
    }
    psq0 += __shfl_xor(psq0, 1); psq0 += __shfl_xor(psq0, 2);
    psq1 += __shfl_xor(psq1, 1); psq1 += __shfl_xor(psq1, 2);
    psq2 += __shfl_xor(psq2, 1); psq2 += __shfl_xor(psq2, 2);
    psq3 += __shfl_xor(psq3, 1); psq3 += __shfl_xor(psq3, 2);
    float mysq = (cg0 == 0) ? psq0 : (cg0 == 1) ? psq1 : (cg0 == 2) ? psq2 : psq3;
    sp[pq * 4 + cg0] = make_float2(mysq, p_mine);

    // transpose in-register: write 4 channels x 1 pixel as 8 B chunks
#pragma unroll
    for (int it = 0; it < 2; ++it) {
        const int cg = cg0 + it * 4;
        short4 o0 = { bfs(v[it*4+0].x), bfs(v[it*4+1].x), bfs(v[it*4+2].x), bfs(v[it*4+3].x) };
        short4 o1 = { bfs(v[it*4+0].y), bfs(v[it*4+1].y), bfs(v[it*4+2].y), bfs(v[it*4+3].y) };
        short4 o2 = { bfs(v[it*4+0].z), bfs(v[it*4+1].z), bfs(v[it*4+2].z), bfs(v[it*4+3].z) };
        short4 o3 = { bfs(v[it*4+0].w), bfs(v[it*4+1].w), bfs(v[it*4+2].w), bfs(v[it*4+3].w) };
        *(short4*)&fb[pq * 4 + 0][cg * 4] = o0;
        *(short4*)&fb[pq * 4 + 1][cg * 4] = o1;
        *(short4*)&fb[pq * 4 + 2][cg * 4] = o2;
        *(short4*)&fb[pq * 4 + 3][cg * 4] = o3;
    }
    __syncthreads();

    const int lr = l & 15;   // col-in-tile (pixel j = tj*16+lr)
    const int lk = l >> 4;   // k-group; acc rows qi = lk*4+r

    bf16x8 af[4];
#pragma unroll
    for (int r = 0; r < 4; ++r)
        af[r] = *(const bf16x8*)&fb[(w * 4 + r) * 16 + lr][lk * 8];

    // log2-domain: E2 = L100*dot - L50*(sq_i+sq_j) + CSPL*dsp_px2
    const float L50  = 72.134752f;      // 50*log2(e)
    const float L100 = 144.269504f;     // 100*log2(e)
    const float CSPL = -4.3333804e-8f;  // -log2(e)/(2*256*65025)

    float a[4][4];
    float api[4][4];
#pragma unroll
    for (int tii = 0; tii < 4; ++tii)
#pragma unroll
        for (int r = 0; r < 4; ++r) {
            const int qi = lk * 4 + r;
            const float dq = (float)(qi - lr);
            a[tii][r] = fmaf(dq * dq, CSPL, -L50 * sp[(w * 4 + tii) * 16 + qi].x);
            api[tii][r] = 0.f;
        }

    const f32x4 zero = {0.f, 0.f, 0.f, 0.f};
    const float tif = (float)(w * 4);

#pragma unroll 2
    for (int tj = 0; tj < 16; ++tj) {
        const bf16x8 bfj = *(const bf16x8*)&fb[tj * 16 + lr][lk * 8];
        const float2 spc = sp[tj * 16 + lr];          // {sq_j, p_j}
        const float bbase = -L50 * spc.x;
        const float tjf = (float)tj;

        f32x4 acc[4];
#pragma unroll
        for (int tii = 0; tii < 4; ++tii)
            acc[tii] = __builtin_amdgcn_mfma_f32_16x16x32_bf16(af[tii], bfj, zero, 0, 0, 0);

        float E[4][4];
        float mx = -1e30f;
#pragma unroll
        for (int tii = 0; tii < 4; ++tii) {
            const float dyf = tif + (float)tii - tjf;
            const float bj = fmaf(dyf * dyf, CSPL, bbase);
#pragma unroll
            for (int r = 0; r < 4; ++r) {
                E[tii][r] = fmaf(L100, acc[tii][r], a[tii][r] + bj);
                mx = fmaxf(mx, E[tii][r]);
            }
        }

        // exp2(x < -126) == 0.0f exactly -> whole tj-group skippable
        if (__any(mx > -126.f)) {
#pragma unroll
            for (int tii = 0; tii < 4; ++tii) {
                const bool tdiag = (w * 4 + tii) == tj;
#pragma unroll
                for (int r = 0; r < 4; ++r) {
                    float e2 = E[tii][r];
                    if (tdiag && (lk * 4 + r) == lr) e2 = 0.f;  // exact diagonal
                    api[tii][r] = fmaf(__builtin_amdgcn_exp2f(e2), spc.y, api[tii][r]);
                }
            }
        }
    }

    // ---- epilogue: weight locally (p_i uniform across the 16 lr lanes),
    //      then one full-wave reduce for {assoc, cut} ----
    float assoc = 0.f, cut = 0.f;
#pragma unroll
    for (int tii = 0; tii < 4; ++tii)
#pragma unroll
        for (int r = 0; r < 4; ++r) {
            const float pi = sp[(w * 4 + tii) * 16 + lk * 4 + r].y;  // broadcast
            assoc += api[tii][r];
            cut   = fmaf(1.f - pi, api[tii][r], cut);
        }
#pragma unroll
    for (int off = 32; off; off >>= 1) {
        assoc += __shfl_down(assoc, off);
        cut   += __shfl_down(cut,  off);
    }
    if (l == 0) { red[2 * w] = assoc; red[2 * w + 1] = cut; }
    __syncthreads();
    if (t == 0) {
        float aa = red[0] + red[2] + red[4] + red[6];
        float cc = red[1] + red[3] + red[5] + red[7];
        ws[b] = cc / (aa + 1e-5f);     // plain store, no atomic
    }
}

__global__ __launch_bounds__(256)
void ncut_reduce_kernel(const float* __restrict__ ws, float* __restrict__ out)
{
    __shared__ float red[4];
    const int t = threadIdx.x;
    float s = ws[t] + ws[t + 256] + ws[t + 512] + ws[t + 768];
#pragma unroll
    for (int off = 32; off; off >>= 1)
        s += __shfl_down(s, off);
    if ((t & 63) == 0) red[t >> 6] = s;
    __syncthreads();
    if (t == 0)
        out[0] = (red[0] + red[1] + red[2] + red[3]) * (1.0f / 1024.0f);
}

extern "C" void kernel_launch(void* const* d_in, const int* in_sizes, int n_in,
                              void* d_out, int out_size, void* d_ws, size_t ws_size,
                              hipStream_t stream)
{
    const float* pred = (const float*)d_in[0];   // (4,1,256,256) f32
    const float* feat = (const float*)d_in[1];   // (4,32,256,256) f32
    float* out = (float*)d_out;                  // scalar f32
    float* ws  = (float*)d_ws;                   // per-patch losses (1024 f32)

    ncut_mfma_kernel<<<1024, 256, 0, stream>>>(pred, feat, ws);
    ncut_reduce_kernel<<<1, 256, 0, stream>>>(ws, out);
}